// Round 4
// baseline (152.430 us; speedup 1.0000x reference)
//
#include <hip/hip_runtime.h>
#include <cmath>

#define FIN 256
#define FQK 256
#define SCALING 0.0625f  // FQK^-0.5 = 1/16
#define MAX_SEG 256

typedef __bf16 bf16_t;
typedef bf16_t bf16x8 __attribute__((ext_vector_type(8)));
typedef float  f32x4  __attribute__((ext_vector_type(4)));

__device__ __forceinline__ unsigned short f2bf(float f) {
    unsigned int u = __float_as_uint(f);
    u += 0x7FFFu + ((u >> 16) & 1u);   // RNE
    return (unsigned short)(u >> 16);
}
__device__ __forceinline__ float bf_lo(unsigned int w) { return __uint_as_float(w << 16); }
__device__ __forceinline__ float bf_hi(unsigned int w) { return __uint_as_float(w & 0xFFFF0000u); }

// ---------------------------------------------------------------------------
// Kernel 1: Mb[f][g] = bf16( SCALING * sum_c W[c][f] * W[256+c][g] )
// ---------------------------------------------------------------------------
__global__ __launch_bounds__(FIN) void compute_M_kernel(const float* __restrict__ W,
                                                        unsigned short* __restrict__ Mb) {
    const int f = blockIdx.x;
    const int g = threadIdx.x;
    const float* __restrict__ Wq = W;
    const float* __restrict__ Wk = W + FQK * FIN;
    float acc = 0.f;
#pragma unroll 8
    for (int c = 0; c < FQK; ++c) {
        acc += Wq[c * FIN + f] * Wk[c * FIN + g];
    }
    Mb[f * FIN + g] = f2bf(acc * SCALING);
}

// ---------------------------------------------------------------------------
// Kernel 2: y[n][f] = sum_g x[n][g] * M[g][f], bf16 MFMA 16x16x32, y bf16.
// 32-row tile per block (grid 625 -> 2.4 blocks/CU), 4 waves; wave wv owns
// f-slice wv*64..+64 (2 m-tiles x 4 f-tiles per wave).
// ---------------------------------------------------------------------------
#define ASTRIDE 40  // bf16 elems per LDS row (80 B; 16B-aligned b128 reads)
#define GROWS   32

__global__ __launch_bounds__(256) void gemm_y_kernel(const float* __restrict__ x,
                                                     const unsigned short* __restrict__ Mb,
                                                     unsigned short* __restrict__ y, int N) {
    __shared__ unsigned short sA[GROWS * ASTRIDE];

    const int t    = threadIdx.x;
    const int wv   = t >> 6;
    const int lane = t & 63;
    const int q    = lane >> 4;    // quad 0..3
    const int m16  = lane & 15;
    const int n0   = blockIdx.x * GROWS;
    const int f0   = wv * 64;

    f32x4 acc[2][4] = {};          // [m-tile][f-tile]

    // staging: thread t -> row t>>3 (0..31), k-col (t&7)*4
    const int srow = t >> 3;
    const int skc  = (t & 7) * 4;

    for (int kc = 0; kc < FIN; kc += 32) {
        {
            const int n = n0 + srow;
            float4 v = make_float4(0.f, 0.f, 0.f, 0.f);
            if (n < N) v = *(const float4*)(x + (size_t)n * FIN + kc + skc);
            unsigned short* p = &sA[srow * ASTRIDE + skc];
            p[0] = f2bf(v.x); p[1] = f2bf(v.y); p[2] = f2bf(v.z); p[3] = f2bf(v.w);
        }
        __syncthreads();

        bf16x8 afrag[2];
#pragma unroll
        for (int mt = 0; mt < 2; ++mt)
            afrag[mt] = *(const bf16x8*)&sA[(mt * 16 + m16) * ASTRIDE + q * 8];
#pragma unroll
        for (int ft = 0; ft < 4; ++ft) {
            const int f = f0 + ft * 16 + m16;
            union { uint4 u; bf16x8 v; } bu;
            bu.u = *(const uint4*)(Mb + (size_t)f * FIN + kc + q * 8);
#pragma unroll
            for (int mt = 0; mt < 2; ++mt)
                acc[mt][ft] = __builtin_amdgcn_mfma_f32_16x16x32_bf16(afrag[mt], bu.v,
                                                                     acc[mt][ft], 0, 0, 0);
        }
        __syncthreads();
    }

    // store: within 16x16 tile, col = m16 (f), row = q*4 + r (n)
#pragma unroll
    for (int mt = 0; mt < 2; ++mt) {
#pragma unroll
        for (int r = 0; r < 4; ++r) {
            const int n = n0 + mt * 16 + q * 4 + r;
            if (n < N) {
#pragma unroll
                for (int ft = 0; ft < 4; ++ft)
                    y[(size_t)n * FIN + f0 + ft * 16 + m16] = f2bf(acc[mt][ft][r]);
            }
        }
    }
}

// ---------------------------------------------------------------------------
// Kernel 3: one wave per node. Fused lower_bound + edge-dot + exp + segsum +
// normalize. Lane = (slot s 0..7, sublane j 0..7); 8 edges per iteration;
// lane reads uint4 idx i*8+j (i=0..3) of the dest row -> 128 B contiguous
// per slot-group; 3-step butterfly over j; 3-step cross-slot reduce at end.
// ---------------------------------------------------------------------------
__global__ __launch_bounds__(256) void node_edge_kernel(const float* __restrict__ x,
                                                        const unsigned short* __restrict__ y,
                                                        const int* __restrict__ src,
                                                        const int* __restrict__ dest,
                                                        float* __restrict__ out,
                                                        int N, int E) {
    __shared__ float exlds[4][MAX_SEG];

    const int w    = threadIdx.x >> 6;
    const int lane = threadIdx.x & 63;
    const int n    = blockIdx.x * 4 + w;
    const int s    = lane >> 3;   // slot 0..7
    const int j    = lane & 7;    // sublane 0..7

    // per-wave segment bounds: lane 0 -> lower_bound(n), lane 1 -> lower_bound(n+1)
    int bound = 0;
    if (lane < 2) {
        const int target = n + lane;
        int lo = 0, hi = E;
        while (lo < hi) {
            const int mid = (lo + hi) >> 1;
            if (src[mid] < target) lo = mid + 1; else hi = mid;
        }
        bound = lo;
    }
    const int s0 = __shfl(bound, 0, 64);
    const int s1 = __shfl(bound, 1, 64);
    const int cnt = (n < N) ? (s1 - s0) : 0;

    float inv = 0.f;

    if (cnt > 0) {
        // x[n] slice for this lane: elems [(i*8+j)*8, +8) for i=0..3
        float4 xf[8];
#pragma unroll
        for (int i = 0; i < 4; ++i) {
            const int off = (i * 8 + j) * 8;
            xf[i * 2 + 0] = *(const float4*)(x + (size_t)n * FIN + off);
            xf[i * 2 + 1] = *(const float4*)(x + (size_t)n * FIN + off + 4);
        }

        float sum = 0.f;
        for (int base = 0; base < cnt; base += 64) {
            const int m = min(64, cnt - base);
            const int vd = (lane < m) ? dest[s0 + base + lane] : 0;
            const int nit = (m + 7) >> 3;
            for (int it = 0; it < nit; ++it) {
                const int  eg    = it * 8 + s;
                const bool valid = eg < m;
                const int  d     = __shfl(vd, eg, 64);
                const uint4* __restrict__ yr = (const uint4*)(y + (size_t)(valid ? d : 0) * FIN);
                uint4 qv[4];
#pragma unroll
                for (int i = 0; i < 4; ++i) qv[i] = yr[i * 8 + j];
                float acc = 0.f;
#pragma unroll
                for (int i = 0; i < 4; ++i) {
                    const float4 xa = xf[i * 2 + 0];
                    const float4 xb = xf[i * 2 + 1];
                    acc += bf_lo(qv[i].x) * xa.x + bf_hi(qv[i].x) * xa.y
                         + bf_lo(qv[i].y) * xa.z + bf_hi(qv[i].y) * xa.w
                         + bf_lo(qv[i].z) * xb.x + bf_hi(qv[i].z) * xb.y
                         + bf_lo(qv[i].w) * xb.z + bf_hi(qv[i].w) * xb.w;
                }
                acc += __shfl_xor(acc, 1, 64);
                acc += __shfl_xor(acc, 2, 64);
                acc += __shfl_xor(acc, 4, 64);
                if (valid) {
                    const float ex = __expf(acc);   // uniform across the 8 sublanes
                    sum += ex;
                    const int idx = base + eg;
                    if (j == 0 && idx < MAX_SEG) exlds[w][idx] = ex;
                }
            }
        }
        // cross-slot reduce over lane bits 3,4,5
        sum += __shfl_xor(sum, 8, 64);
        sum += __shfl_xor(sum, 16, 64);
        sum += __shfl_xor(sum, 32, 64);
        inv = 1.0f / sum;
    }

    __syncthreads();   // all threads reach; orders LDS w->r

    if (cnt > 0) {
        const int lim = cnt < MAX_SEG ? cnt : MAX_SEG;
        for (int i = lane; i < lim; i += 64)
            out[s0 + i] = exlds[w][i] * inv;
    }
}

// ---------------------------------------------------------------------------
extern "C" void kernel_launch(void* const* d_in, const int* in_sizes, int n_in,
                              void* d_out, int out_size, void* d_ws, size_t ws_size,
                              hipStream_t stream) {
    const float* x  = (const float*)d_in[0];
    const int*   ei = (const int*)d_in[1];   // src = ei[0:E], dest = ei[E:2E]
    const float* W  = (const float*)d_in[2];
    float* out = (float*)d_out;

    const int N = in_sizes[0] / FIN;
    const int E = in_sizes[1] / 2;

    // workspace layout
    unsigned short* Mb = (unsigned short*)d_ws;       // 256*256 bf16
    unsigned short* y  = Mb + (size_t)FIN * FIN;      // N*256 bf16

    compute_M_kernel<<<FIN, FIN, 0, stream>>>(W, Mb);

    gemm_y_kernel<<<(N + GROWS - 1) / GROWS, 256, 0, stream>>>(x, Mb, y, N);

    node_edge_kernel<<<(N + 3) / 4, 256, 0, stream>>>(x, y, ei, ei + E, out, N, E);
}

// Round 5
// 141.034 us; speedup vs baseline: 1.0808x; 1.0808x over previous
//
#include <hip/hip_runtime.h>
#include <cmath>

#define FIN 256
#define FQK 256
#define SCALING 0.0625f  // FQK^-0.5 = 1/16
#define MAX_SEG 256

typedef __bf16 bf16_t;
typedef bf16_t bf16x8 __attribute__((ext_vector_type(8)));
typedef float  f32x4  __attribute__((ext_vector_type(4)));

__device__ __forceinline__ unsigned short f2bf(float f) {
    unsigned int u = __float_as_uint(f);
    u += 0x7FFFu + ((u >> 16) & 1u);   // RNE
    return (unsigned short)(u >> 16);
}
__device__ __forceinline__ float bf_lo(unsigned int w) { return __uint_as_float(w << 16); }
__device__ __forceinline__ float bf_hi(unsigned int w) { return __uint_as_float(w & 0xFFFF0000u); }

// ---------------------------------------------------------------------------
// Kernel 1: Mb[f][g] = bf16( SCALING * sum_c W[c][f] * W[256+c][g] )
// ---------------------------------------------------------------------------
__global__ __launch_bounds__(FIN) void compute_M_kernel(const float* __restrict__ W,
                                                        unsigned short* __restrict__ Mb) {
    const int f = blockIdx.x;
    const int g = threadIdx.x;
    const float* __restrict__ Wq = W;
    const float* __restrict__ Wk = W + FQK * FIN;
    float acc = 0.f;
#pragma unroll 8
    for (int c = 0; c < FQK; ++c) {
        acc += Wq[c * FIN + f] * Wk[c * FIN + g];
    }
    Mb[f * FIN + g] = f2bf(acc * SCALING);
}

// ---------------------------------------------------------------------------
// Kernel 2: y[n][f] = sum_g x[n][g] * M[g][f], bf16 MFMA 16x16x32, y bf16.
// 32-row tile per block (grid 625), 4 waves; wave wv owns f-slice wv*64..+64.
// ---------------------------------------------------------------------------
#define ASTRIDE 40
#define GROWS   32

__global__ __launch_bounds__(256) void gemm_y_kernel(const float* __restrict__ x,
                                                     const unsigned short* __restrict__ Mb,
                                                     unsigned short* __restrict__ y, int N) {
    __shared__ unsigned short sA[GROWS * ASTRIDE];

    const int t    = threadIdx.x;
    const int wv   = t >> 6;
    const int lane = t & 63;
    const int q    = lane >> 4;
    const int m16  = lane & 15;
    const int n0   = blockIdx.x * GROWS;
    const int f0   = wv * 64;

    f32x4 acc[2][4] = {};

    const int srow = t >> 3;
    const int skc  = (t & 7) * 4;

    for (int kc = 0; kc < FIN; kc += 32) {
        {
            const int n = n0 + srow;
            float4 v = make_float4(0.f, 0.f, 0.f, 0.f);
            if (n < N) v = *(const float4*)(x + (size_t)n * FIN + kc + skc);
            unsigned short* p = &sA[srow * ASTRIDE + skc];
            p[0] = f2bf(v.x); p[1] = f2bf(v.y); p[2] = f2bf(v.z); p[3] = f2bf(v.w);
        }
        __syncthreads();

        bf16x8 afrag[2];
#pragma unroll
        for (int mt = 0; mt < 2; ++mt)
            afrag[mt] = *(const bf16x8*)&sA[(mt * 16 + m16) * ASTRIDE + q * 8];
#pragma unroll
        for (int ft = 0; ft < 4; ++ft) {
            const int f = f0 + ft * 16 + m16;
            union { uint4 u; bf16x8 v; } bu;
            bu.u = *(const uint4*)(Mb + (size_t)f * FIN + kc + q * 8);
#pragma unroll
            for (int mt = 0; mt < 2; ++mt)
                acc[mt][ft] = __builtin_amdgcn_mfma_f32_16x16x32_bf16(afrag[mt], bu.v,
                                                                     acc[mt][ft], 0, 0, 0);
        }
        __syncthreads();
    }

#pragma unroll
    for (int mt = 0; mt < 2; ++mt) {
#pragma unroll
        for (int r = 0; r < 4; ++r) {
            const int n = n0 + mt * 16 + q * 4 + r;
            if (n < N) {
#pragma unroll
                for (int ft = 0; ft < 4; ++ft)
                    y[(size_t)n * FIN + f0 + ft * 16 + m16] = f2bf(acc[mt][ft][r]);
            }
        }
    }
}

// ---------------------------------------------------------------------------
// Kernel 3: seg[n] = lower_bound(src, n)  (separate kernel: 20K-way parallel,
// overlaps with gemm; fusing it into node_edge regressed -15us in R4)
// ---------------------------------------------------------------------------
__global__ __launch_bounds__(256) void seg_kernel(const int* __restrict__ src,
                                                  int* __restrict__ seg, int N, int E) {
    const int n = blockIdx.x * 256 + threadIdx.x;
    if (n > N) return;
    int lo = 0, hi = E;
    while (lo < hi) {
        const int mid = (lo + hi) >> 1;
        if (src[mid] < n) lo = mid + 1; else hi = mid;
    }
    seg[n] = lo;
}

// ---------------------------------------------------------------------------
// Kernel 4: one wave per node; 4 slots x 16 sublanes; edge loop unrolled x2
// (two independent edges per slot in flight -> 4 outstanding uint4 loads/lane).
// 256 B contiguous per 16-lane slot-group per load instruction (coalesced).
// ---------------------------------------------------------------------------
__global__ __launch_bounds__(256) void node_edge_kernel(const float* __restrict__ x,
                                                        const unsigned short* __restrict__ y,
                                                        const int* __restrict__ dest,
                                                        const int* __restrict__ seg,
                                                        float* __restrict__ out, int N) {
    __shared__ float exlds[4][MAX_SEG];

    const int w    = threadIdx.x >> 6;
    const int lane = threadIdx.x & 63;
    const int n    = blockIdx.x * 4 + w;
    const int g    = lane >> 4;   // slot 0..3
    const int j    = lane & 15;   // sublane 0..15

    int   s0 = 0, cnt = 0;
    float inv = 0.f;

    if (n < N) {
        s0 = seg[n];
        cnt = seg[n + 1] - s0;
    }

    if (cnt > 0) {
        // x[n] slices: xf[u*2+h] = x[n][u*128 + j*8 + h*4 .. +4]
        float4 xf[4];
#pragma unroll
        for (int u = 0; u < 2; ++u) {
            xf[u * 2 + 0] = *(const float4*)(x + (size_t)n * FIN + u * 128 + j * 8);
            xf[u * 2 + 1] = *(const float4*)(x + (size_t)n * FIN + u * 128 + j * 8 + 4);
        }

        float sum = 0.f;
        for (int base = 0; base < cnt; base += 64) {
            const int m = min(64, cnt - base);
            const int vd = (lane < m) ? dest[s0 + base + lane] : 0;
            const int nit = (m + 3) >> 2;
            for (int it = 0; it < nit; it += 2) {
                const int  eg0 = it * 4 + g;
                const int  eg1 = eg0 + 4;          // (it+1)*4+g, always <= 63
                const bool v0  = eg0 < m;
                const bool v1  = eg1 < m;
                const int  d0  = __shfl(vd, eg0, 64);
                const int  d1  = __shfl(vd, eg1, 64);
                const uint4* __restrict__ yr0 = (const uint4*)(y + (size_t)(v0 ? d0 : 0) * FIN);
                const uint4* __restrict__ yr1 = (const uint4*)(y + (size_t)(v1 ? d1 : 0) * FIN);
                // 4 independent loads in flight
                const uint4 q00 = yr0[j];
                const uint4 q01 = yr0[16 + j];
                const uint4 q10 = yr1[j];
                const uint4 q11 = yr1[16 + j];

                float a0 = 0.f, a1 = 0.f;
                {
                    const float4 xa = xf[0], xb = xf[1], xc = xf[2], xd = xf[3];
                    a0 += bf_lo(q00.x) * xa.x + bf_hi(q00.x) * xa.y
                        + bf_lo(q00.y) * xa.z + bf_hi(q00.y) * xa.w
                        + bf_lo(q00.z) * xb.x + bf_hi(q00.z) * xb.y
                        + bf_lo(q00.w) * xb.z + bf_hi(q00.w) * xb.w;
                    a0 += bf_lo(q01.x) * xc.x + bf_hi(q01.x) * xc.y
                        + bf_lo(q01.y) * xc.z + bf_hi(q01.y) * xc.w
                        + bf_lo(q01.z) * xd.x + bf_hi(q01.z) * xd.y
                        + bf_lo(q01.w) * xd.z + bf_hi(q01.w) * xd.w;
                    a1 += bf_lo(q10.x) * xa.x + bf_hi(q10.x) * xa.y
                        + bf_lo(q10.y) * xa.z + bf_hi(q10.y) * xa.w
                        + bf_lo(q10.z) * xb.x + bf_hi(q10.z) * xb.y
                        + bf_lo(q10.w) * xb.z + bf_hi(q10.w) * xb.w;
                    a1 += bf_lo(q11.x) * xc.x + bf_hi(q11.x) * xc.y
                        + bf_lo(q11.y) * xc.z + bf_hi(q11.y) * xc.w
                        + bf_lo(q11.z) * xd.x + bf_hi(q11.z) * xd.y
                        + bf_lo(q11.w) * xd.z + bf_hi(q11.w) * xd.w;
                }
                // interleaved butterflies (independent chains)
                a0 += __shfl_xor(a0, 1, 64);
                a1 += __shfl_xor(a1, 1, 64);
                a0 += __shfl_xor(a0, 2, 64);
                a1 += __shfl_xor(a1, 2, 64);
                a0 += __shfl_xor(a0, 4, 64);
                a1 += __shfl_xor(a1, 4, 64);
                a0 += __shfl_xor(a0, 8, 64);
                a1 += __shfl_xor(a1, 8, 64);

                if (v0) {
                    const float ex = __expf(a0);
                    sum += ex;
                    const int idx = base + eg0;
                    if (j == 0 && idx < MAX_SEG) exlds[w][idx] = ex;
                }
                if (v1) {
                    const float ex = __expf(a1);
                    sum += ex;
                    const int idx = base + eg1;
                    if (j == 0 && idx < MAX_SEG) exlds[w][idx] = ex;
                }
            }
        }
        sum += __shfl_xor(sum, 16, 64);
        sum += __shfl_xor(sum, 32, 64);
        inv = 1.0f / sum;
    }

    __syncthreads();

    if (cnt > 0) {
        const int lim = cnt < MAX_SEG ? cnt : MAX_SEG;
        for (int i = lane; i < lim; i += 64)
            out[s0 + i] = exlds[w][i] * inv;
    }
}

// ---------------------------------------------------------------------------
extern "C" void kernel_launch(void* const* d_in, const int* in_sizes, int n_in,
                              void* d_out, int out_size, void* d_ws, size_t ws_size,
                              hipStream_t stream) {
    const float* x  = (const float*)d_in[0];
    const int*   ei = (const int*)d_in[1];
    const float* W  = (const float*)d_in[2];
    float* out = (float*)d_out;

    const int N = in_sizes[0] / FIN;
    const int E = in_sizes[1] / 2;

    unsigned short* Mb  = (unsigned short*)d_ws;           // 256*256 bf16
    unsigned short* y   = Mb + (size_t)FIN * FIN;          // N*256 bf16
    int*            seg = (int*)(y + (size_t)N * FIN);     // N+1

    compute_M_kernel<<<FIN, FIN, 0, stream>>>(W, Mb);

    gemm_y_kernel<<<(N + GROWS - 1) / GROWS, 256, 0, stream>>>(x, Mb, y, N);

    seg_kernel<<<(N + 256) / 256, 256, 0, stream>>>(ei, seg, N, E);

    node_edge_kernel<<<(N + 3) / 4, 256, 0, stream>>>(x, y, ei + E, seg, out, N);
}